// Round 9
// baseline (415.587 us; speedup 1.0000x reference)
//
#include <hip/hip_runtime.h>

// ---------------------------------------------------------------------------
// MHA forward: B=4, S=2048, D=1024, H=16, DH=64
// bf16 MFMA (16x16x32), f32 accumulate.
// r8 changes: attn QBLK 16->32 per wave (halve per-work K/V LDS reads);
//             fuse Q/K/V projections into one 1536-block launch (occ 2->6/CU).
// ---------------------------------------------------------------------------

typedef __bf16 bf16x8 __attribute__((ext_vector_type(8)));
typedef __bf16 bf16x4 __attribute__((ext_vector_type(4)));
typedef float f32x4 __attribute__((ext_vector_type(4)));

#define GLAS __attribute__((address_space(1)))
#define LDSAS __attribute__((address_space(3)))

__device__ __forceinline__ void gl16(const void* g, void* l) {
  __builtin_amdgcn_global_load_lds((GLAS void*)const_cast<void*>(g),
                                   (LDSAS void*)l, 16, 0, 0);
}

// ---------------------------------------------------------------------------
// Weight transpose + f32->bf16 (+scale): W[k][n] -> WT[n][k]
// ---------------------------------------------------------------------------
__global__ __launch_bounds__(256) void wt_cvt(const float* __restrict__ w,
                                              __bf16* __restrict__ wt, float scl) {
  __shared__ float t[32][33];
  const int n0 = blockIdx.x * 32, k0 = blockIdx.y * 32;
  const int x = threadIdx.x, y = threadIdx.y; // 32 x 8
#pragma unroll
  for (int i = 0; i < 32; i += 8) t[y + i][x] = w[(k0 + y + i) * 1024 + n0 + x];
  __syncthreads();
#pragma unroll
  for (int i = 0; i < 32; i += 8)
    wt[(n0 + y + i) * 1024 + (k0 + x)] = (__bf16)(t[x][y + i] * scl);
}

// ---------------------------------------------------------------------------
// Activation f32 -> bf16 (vectorized x8)
// ---------------------------------------------------------------------------
__global__ __launch_bounds__(256) void cvt_k(const float* __restrict__ in,
                                             __bf16* __restrict__ out) {
  const int i = (blockIdx.x * 256 + threadIdx.x) * 8;
  const float4 f0 = *(const float4*)(in + i);
  const float4 f1 = *(const float4*)(in + i + 4);
  bf16x8 o;
  o[0] = (__bf16)f0.x; o[1] = (__bf16)f0.y; o[2] = (__bf16)f0.z; o[3] = (__bf16)f0.w;
  o[4] = (__bf16)f1.x; o[5] = (__bf16)f1.y; o[6] = (__bf16)f1.z; o[7] = (__bf16)f1.w;
  *(bf16x8*)(out + i) = o;
}

// ---------------------------------------------------------------------------
// Fused QKV projection GEMM. grid (8, 192): sel = y>>6 (0=Q,1=K,2=V),
// m0 = (y&63)*128. C[8192][1024] = A_sel * WT_sel^T + b_sel.
// 128x128 tile, BK=64, 4 waves; global_load_lds(16B) with pre-swizzled src.
// Q,K out: bf16 [B,H,S,DH] ; V out: bf16 [B,H,DH,S].
// ---------------------------------------------------------------------------
__global__ __launch_bounds__(256) void gemm_qkv(
    const __bf16* __restrict__ Abase, const __bf16* __restrict__ Wbase,
    const float* __restrict__ bq, const float* __restrict__ bk,
    const float* __restrict__ bv, float sclq,
    __bf16* __restrict__ Qp, __bf16* __restrict__ Kp, __bf16* __restrict__ Vtp) {
  __shared__ __align__(16) char smem[32768];
  const int tid = threadIdx.x, wid = tid >> 6, lane = tid & 63;
  const int wr = wid >> 1, wc = wid & 1;
  const int sel = blockIdx.y >> 6;
  const int m0 = (blockIdx.y & 63) * 128, n0 = blockIdx.x * 128;
  const int lr = lane & 15, lg = lane >> 4;

  const int srow = lane >> 3;
  const int scl8 = (lane & 7) ^ srow;
  const __bf16* A  = Abase + sel * 8388608;
  const __bf16* BT = Wbase + sel * 1048576;
  const __bf16* Ab = A + (m0 + wid * 32 + srow) * 1024 + scl8 * 8;
  const __bf16* Bb = BT + (n0 + wid * 32 + srow) * 1024 + scl8 * 8;
  char* AsW = smem + wid * 4096;
  char* BsW = smem + 16384 + wid * 4096;

  f32x4 acc[4][4] = {};

  for (int k0 = 0; k0 < 1024; k0 += 64) {
#pragma unroll
    for (int i = 0; i < 4; ++i) {
      gl16(Ab + i * 8192 + k0, AsW + i * 1024);
      gl16(Bb + i * 8192 + k0, BsW + i * 1024);
    }
    __syncthreads();
#pragma unroll
    for (int ks = 0; ks < 2; ++ks) {
      bf16x8 af[4], bfv[4];
      const int co = (ks * 64 + lg * 16) ^ ((lr & 7) << 4);
#pragma unroll
      for (int i = 0; i < 4; ++i) {
        af[i]  = *(const bf16x8*)(smem + (wr * 64 + i * 16 + lr) * 128 + co);
        bfv[i] = *(const bf16x8*)(smem + 16384 + (wc * 64 + i * 16 + lr) * 128 + co);
      }
#pragma unroll
      for (int i = 0; i < 4; ++i)
#pragma unroll
        for (int j = 0; j < 4; ++j)
          acc[i][j] = __builtin_amdgcn_mfma_f32_16x16x32_bf16(af[i], bfv[j], acc[i][j], 0, 0, 0);
    }
    __syncthreads();
  }

  const float* bias = sel == 0 ? bq : (sel == 1 ? bk : bv);
  const float bsc = sel == 0 ? sclq : 1.f;
  __bf16* outp = sel == 0 ? Qp : (sel == 1 ? Kp : Vtp);
#pragma unroll
  for (int i = 0; i < 4; ++i)
#pragma unroll
    for (int j = 0; j < 4; ++j) {
      const int n = n0 + wc * 64 + j * 16 + lr;
      const float bb = bias[n] * bsc;
#pragma unroll
      for (int r = 0; r < 4; ++r) {
        const int m = m0 + wr * 64 + i * 16 + lg * 4 + r;
        const float v = acc[i][j][r] + bb;
        const int b = m >> 11, s = m & 2047;
        const int h = n >> 6, dh = n & 63;
        if (sel < 2)
          outp[(((b * 16 + h) * 2048 + s) << 6) + dh] = (__bf16)v;
        else
          outp[(((b * 16 + h) * 64 + dh) << 11) + s] = (__bf16)v;
      }
    }
}

// ---------------------------------------------------------------------------
// Output projection GEMM: out f32 = ctx(bf16) * WoT^T + bo
// ---------------------------------------------------------------------------
__global__ __launch_bounds__(256) void gemm_o(const __bf16* __restrict__ A,
                                              const __bf16* __restrict__ BT,
                                              const float* __restrict__ bias,
                                              float* __restrict__ outp) {
  __shared__ __align__(16) char smem[32768];
  const int tid = threadIdx.x, wid = tid >> 6, lane = tid & 63;
  const int wr = wid >> 1, wc = wid & 1;
  const int m0 = blockIdx.y * 128, n0 = blockIdx.x * 128;
  const int lr = lane & 15, lg = lane >> 4;

  const int srow = lane >> 3;
  const int scl8 = (lane & 7) ^ srow;
  const __bf16* Ab = A + (m0 + wid * 32 + srow) * 1024 + scl8 * 8;
  const __bf16* Bb = BT + (n0 + wid * 32 + srow) * 1024 + scl8 * 8;
  char* AsW = smem + wid * 4096;
  char* BsW = smem + 16384 + wid * 4096;

  f32x4 acc[4][4] = {};

  for (int k0 = 0; k0 < 1024; k0 += 64) {
#pragma unroll
    for (int i = 0; i < 4; ++i) {
      gl16(Ab + i * 8192 + k0, AsW + i * 1024);
      gl16(Bb + i * 8192 + k0, BsW + i * 1024);
    }
    __syncthreads();
#pragma unroll
    for (int ks = 0; ks < 2; ++ks) {
      bf16x8 af[4], bfv[4];
      const int co = (ks * 64 + lg * 16) ^ ((lr & 7) << 4);
#pragma unroll
      for (int i = 0; i < 4; ++i) {
        af[i]  = *(const bf16x8*)(smem + (wr * 64 + i * 16 + lr) * 128 + co);
        bfv[i] = *(const bf16x8*)(smem + 16384 + (wc * 64 + i * 16 + lr) * 128 + co);
      }
#pragma unroll
      for (int i = 0; i < 4; ++i)
#pragma unroll
        for (int j = 0; j < 4; ++j)
          acc[i][j] = __builtin_amdgcn_mfma_f32_16x16x32_bf16(af[i], bfv[j], acc[i][j], 0, 0, 0);
    }
    __syncthreads();
  }

#pragma unroll
  for (int i = 0; i < 4; ++i)
#pragma unroll
    for (int j = 0; j < 4; ++j) {
      const int n = n0 + wc * 64 + j * 16 + lr;
      const float bb = bias[n];
#pragma unroll
      for (int r = 0; r < 4; ++r) {
        const int m = m0 + wr * 64 + i * 16 + lg * 4 + r;
        outp[m * 1024 + n] = acc[i][j][r] + bb;
      }
    }
}

// ---------------------------------------------------------------------------
// Flash attention, QBLK=32 per wave. Qp,Kp: [B*H][S][64] ; Vt: [B*H][64][S]
// Block = (b,h) x 128 q-rows (4 waves x 32). grid (16, 64).
// Swapped QK^T: sc[qs][cb] = mfma(K, Q_qs) -> lane owns q = q0+qs*16+lr.
// K/V frag reads shared across both q-sets (halves per-work LDS reads).
// Ps buffer reused sequentially for qs=0,1 (wave-local RAW via lgkmcnt).
// ---------------------------------------------------------------------------
__global__ __launch_bounds__(256) void attn_k(const __bf16* __restrict__ Qp,
                                              const __bf16* __restrict__ Kp,
                                              const __bf16* __restrict__ Vt,
                                              __bf16* __restrict__ ctx) {
  __shared__ __align__(16) char smem[40960];
  // Ks: 2x8KB @0 ; Vs: 2x8KB @16384 ; Ps: 4 waves x 2KB @32768
  const int tid = threadIdx.x, wid = tid >> 6, lane = tid & 63;
  const int lr = lane & 15, lg = lane >> 4;
  const int bh = blockIdx.y;
  const int q0 = blockIdx.x * 128 + wid * 32;
  const int S = 2048;

  const int srow = lane >> 3;
  const int scl8 = (lane & 7) ^ srow;
  const __bf16* Kbase = Kp + (bh * S + srow) * 64 + scl8 * 8;
  const __bf16* Vbase = Vt + (bh * 64 + srow) * S + scl8 * 8;
  char* Ps = smem + 32768 + wid * 2048;

  bf16x8 aq[2][2];
#pragma unroll
  for (int qs = 0; qs < 2; ++qs)
#pragma unroll
    for (int ks = 0; ks < 2; ++ks)
      aq[qs][ks] = *(const bf16x8*)(Qp + (bh * S + q0 + qs * 16 + lr) * 64 +
                                    ks * 32 + lg * 8);

  float m_run[2] = {-1e30f, -1e30f}, l_run[2] = {0.f, 0.f};
  f32x4 acc_o[2][4] = {};

  // prologue: stage tile 0 -> buf 0 (chunks wid*2, wid*2+1)
#pragma unroll
  for (int i = 0; i < 2; ++i) {
    const int ch = wid * 2 + i;
    gl16(Kbase + ch * 512, smem + ch * 1024);
    gl16(Vbase + ch * 16384, smem + 16384 + ch * 1024);
  }

  int cur = 0;
  for (int t = 0; t < 32; ++t) {
    __syncthreads(); // drain vmcnt -> buf[cur] ready; all prev reads done
    if (t + 1 < 32) {
      const int kv1 = (t + 1) * 64;
      char* Kd = smem + (cur ^ 1) * 8192;
      char* Vd = smem + 16384 + (cur ^ 1) * 8192;
#pragma unroll
      for (int i = 0; i < 2; ++i) {
        const int ch = wid * 2 + i;
        gl16(Kbase + kv1 * 64 + ch * 512, Kd + ch * 1024);
        gl16(Vbase + kv1 + ch * 16384, Vd + ch * 1024);
      }
    }
    const char* Ks = smem + cur * 8192;
    const char* Vs = smem + 16384 + cur * 8192;

    // ---- QK^T: K frags shared across both q-sets ----
    f32x4 sc[2][4] = {};
    __builtin_amdgcn_s_setprio(1);
#pragma unroll
    for (int cb = 0; cb < 4; ++cb) {
#pragma unroll
      for (int ks = 0; ks < 2; ++ks) {
        const int krow = cb * 16 + lr;
        const bf16x8 kf = *(const bf16x8*)(Ks + krow * 128 +
                                           ((ks * 64 + lg * 16) ^ ((krow & 7) << 4)));
        sc[0][cb] = __builtin_amdgcn_mfma_f32_16x16x32_bf16(kf, aq[0][ks], sc[0][cb], 0, 0, 0);
        sc[1][cb] = __builtin_amdgcn_mfma_f32_16x16x32_bf16(kf, aq[1][ks], sc[1][cb], 0, 0, 0);
      }
    }
    __builtin_amdgcn_s_setprio(0);

    // ---- online softmax per q-set; Ps reused sequentially ----
    bf16x8 pa[2][2];
#pragma unroll
    for (int qs = 0; qs < 2; ++qs) {
      float mx = sc[qs][0][0];
#pragma unroll
      for (int cb = 0; cb < 4; ++cb)
#pragma unroll
        for (int r = 0; r < 4; ++r) mx = fmaxf(mx, sc[qs][cb][r]);
      mx = fmaxf(mx, __shfl_xor(mx, 16, 64));
      mx = fmaxf(mx, __shfl_xor(mx, 32, 64));
      const float mnew = fmaxf(m_run[qs], mx);
      const float corr = __builtin_amdgcn_exp2f(m_run[qs] - mnew);
      m_run[qs] = mnew;
      float rs = 0.f;
#pragma unroll
      for (int cb = 0; cb < 4; ++cb) {
        bf16x4 pk;
#pragma unroll
        for (int r = 0; r < 4; ++r) {
          const float p = __builtin_amdgcn_exp2f(sc[qs][cb][r] - mnew);
          rs += p;
          pk[r] = (__bf16)p;
        }
        *(bf16x4*)(Ps + lr * 128 + ((cb * 32 + lg * 8) ^ ((lr & 7) << 4))) = pk;
      }
      rs += __shfl_xor(rs, 16, 64);
      rs += __shfl_xor(rs, 32, 64);
      l_run[qs] = l_run[qs] * corr + rs;
      float corrv[4];
#pragma unroll
      for (int r = 0; r < 4; ++r) corrv[r] = __shfl(corr, lg * 4 + r, 64);
#pragma unroll
      for (int dhb = 0; dhb < 4; ++dhb)
#pragma unroll
        for (int r = 0; r < 4; ++r) acc_o[qs][dhb][r] *= corrv[r];
      // read back P fragments (wave-local RAW -> lgkmcnt, no barrier)
#pragma unroll
      for (int ks = 0; ks < 2; ++ks)
        pa[qs][ks] = *(const bf16x8*)(Ps + lr * 128 +
                                      ((ks * 64 + lg * 16) ^ ((lr & 7) << 4)));
    }

    // ---- PV: V frags shared across both q-sets ----
    __builtin_amdgcn_s_setprio(1);
#pragma unroll
    for (int dhb = 0; dhb < 4; ++dhb) {
#pragma unroll
      for (int ks = 0; ks < 2; ++ks) {
        const int vrow = dhb * 16 + lr;
        const bf16x8 vf = *(const bf16x8*)(Vs + vrow * 128 +
                                           ((ks * 64 + lg * 16) ^ ((vrow & 7) << 4)));
        acc_o[0][dhb] = __builtin_amdgcn_mfma_f32_16x16x32_bf16(pa[0][ks], vf, acc_o[0][dhb], 0, 0, 0);
        acc_o[1][dhb] = __builtin_amdgcn_mfma_f32_16x16x32_bf16(pa[1][ks], vf, acc_o[1][dhb], 0, 0, 0);
      }
    }
    __builtin_amdgcn_s_setprio(0);
    cur ^= 1;
  }

  // ---- epilogue: ctx[b][s][h*64+dh] = acc / l ----
  const int b = bh >> 4, h = bh & 15;
#pragma unroll
  for (int qs = 0; qs < 2; ++qs) {
    float linv[4];
#pragma unroll
    for (int r = 0; r < 4; ++r) linv[r] = 1.f / __shfl(l_run[qs], lg * 4 + r, 64);
#pragma unroll
    for (int dhb = 0; dhb < 4; ++dhb)
#pragma unroll
      for (int r = 0; r < 4; ++r) {
        const int sr = q0 + qs * 16 + lg * 4 + r;
        const int d = h * 64 + dhb * 16 + lr;
        ctx[(b * 2048 + sr) * 1024 + d] = (__bf16)(acc_o[qs][dhb][r] * linv[r]);
      }
  }
}

// ---------------------------------------------------------------------------
extern "C" void kernel_launch(void* const* d_in, const int* in_sizes, int n_in,
                              void* d_out, int out_size, void* d_ws, size_t ws_size,
                              hipStream_t stream) {
  const float* query = (const float*)d_in[0];
  const float* key   = (const float*)d_in[1];
  const float* value = (const float*)d_in[2];
  const float* Wq = (const float*)d_in[3];
  const float* bq = (const float*)d_in[4];
  const float* Wk = (const float*)d_in[5];
  const float* bk = (const float*)d_in[6];
  const float* Wv = (const float*)d_in[7];
  const float* bv = (const float*)d_in[8];
  const float* Wo = (const float*)d_in[9];
  const float* bo = (const float*)d_in[10];

  char* ws = (char*)d_ws;
  const size_t MiB = 1048576;
  __bf16* Wqkv = (__bf16*)(ws);            // WqT@0, WkT@2MiB, WvT@4MiB
  __bf16* WoT  = (__bf16*)(ws + 6 * MiB);
  __bf16* Abf  = (__bf16*)(ws + 8 * MiB);  // 3 x 16MiB (q,k,v bf16); slot0 reused as ctx
  __bf16* Qp   = (__bf16*)(ws + 56 * MiB);
  __bf16* Kp   = (__bf16*)(ws + 72 * MiB);
  __bf16* Vt   = (__bf16*)(ws + 88 * MiB);
  __bf16* ctx  = Abf;

  const float SCL = 0.125f * 1.44269504088896340736f; // fold /8 and log2(e) into Q

  const dim3 tb(32, 8);
  wt_cvt<<<dim3(32, 32), tb, 0, stream>>>(Wq, Wqkv,              SCL);
  wt_cvt<<<dim3(32, 32), tb, 0, stream>>>(Wk, Wqkv + 1048576,    1.f);
  wt_cvt<<<dim3(32, 32), tb, 0, stream>>>(Wv, Wqkv + 2097152,    1.f);
  wt_cvt<<<dim3(32, 32), tb, 0, stream>>>(Wo, WoT,               1.f);

  cvt_k<<<4096, 256, 0, stream>>>(query, Abf);
  cvt_k<<<4096, 256, 0, stream>>>(key,   Abf + 8388608);
  cvt_k<<<4096, 256, 0, stream>>>(value, Abf + 16777216);

  gemm_qkv<<<dim3(8, 192), 256, 0, stream>>>(Abf, Wqkv, bq, bk, bv, SCL, Qp, Kp, Vt);

  attn_k<<<dim3(16, 64), 256, 0, stream>>>(Qp, Kp, Vt, ctx);

  gemm_o<<<dim3(8, 64), 256, 0, stream>>>(ctx, WoT, bo, (float*)d_out);
}

// Round 11
// 392.626 us; speedup vs baseline: 1.0585x; 1.0585x over previous
//
#include <hip/hip_runtime.h>

// ---------------------------------------------------------------------------
// MHA forward: B=4, S=2048, D=1024, H=16, DH=64
// bf16 MFMA (16x16x32), f32 accumulate.
// r10 changes: (T1) bijective XCD swizzle in gemm_qkv/gemm_o/attn_k so blocks
//              sharing operand panels colocate on one XCD's L2;
//              (T13) defer-max in attn softmax (skip rescale when max growth<8).
// ---------------------------------------------------------------------------

typedef __bf16 bf16x8 __attribute__((ext_vector_type(8)));
typedef __bf16 bf16x4 __attribute__((ext_vector_type(4)));
typedef float f32x4 __attribute__((ext_vector_type(4)));

#define GLAS __attribute__((address_space(1)))
#define LDSAS __attribute__((address_space(3)))

__device__ __forceinline__ void gl16(const void* g, void* l) {
  __builtin_amdgcn_global_load_lds((GLAS void*)const_cast<void*>(g),
                                   (LDSAS void*)l, 16, 0, 0);
}

// ---------------------------------------------------------------------------
// Weight transpose + f32->bf16 (+scale): W[k][n] -> WT[n][k]
// ---------------------------------------------------------------------------
__global__ __launch_bounds__(256) void wt_cvt(const float* __restrict__ w,
                                              __bf16* __restrict__ wt, float scl) {
  __shared__ float t[32][33];
  const int n0 = blockIdx.x * 32, k0 = blockIdx.y * 32;
  const int x = threadIdx.x, y = threadIdx.y; // 32 x 8
#pragma unroll
  for (int i = 0; i < 32; i += 8) t[y + i][x] = w[(k0 + y + i) * 1024 + n0 + x];
  __syncthreads();
#pragma unroll
  for (int i = 0; i < 32; i += 8)
    wt[(n0 + y + i) * 1024 + (k0 + x)] = (__bf16)(t[x][y + i] * scl);
}

// ---------------------------------------------------------------------------
// Activation f32 -> bf16 (vectorized x8)
// ---------------------------------------------------------------------------
__global__ __launch_bounds__(256) void cvt_k(const float* __restrict__ in,
                                             __bf16* __restrict__ out) {
  const int i = (blockIdx.x * 256 + threadIdx.x) * 8;
  const float4 f0 = *(const float4*)(in + i);
  const float4 f1 = *(const float4*)(in + i + 4);
  bf16x8 o;
  o[0] = (__bf16)f0.x; o[1] = (__bf16)f0.y; o[2] = (__bf16)f0.z; o[3] = (__bf16)f0.w;
  o[4] = (__bf16)f1.x; o[5] = (__bf16)f1.y; o[6] = (__bf16)f1.z; o[7] = (__bf16)f1.w;
  *(bf16x8*)(out + i) = o;
}

// ---------------------------------------------------------------------------
// Fused QKV projection GEMM. 1536 blocks, XCD-swizzled: each XCD owns a
// contiguous by-range -> A-slice + B stay L2-resident across re-reads.
// sel = by>>6 (0=Q,1=K,2=V), m0 = (by&63)*128, n0 = bx*128.
// ---------------------------------------------------------------------------
__global__ __launch_bounds__(256) void gemm_qkv(
    const __bf16* __restrict__ Abase, const __bf16* __restrict__ Wbase,
    const float* __restrict__ bq, const float* __restrict__ bk,
    const float* __restrict__ bv, float sclq,
    __bf16* __restrict__ Qp, __bf16* __restrict__ Kp, __bf16* __restrict__ Vtp) {
  __shared__ __align__(16) char smem[32768];
  const int tid = threadIdx.x, wid = tid >> 6, lane = tid & 63;
  const int wr = wid >> 1, wc = wid & 1;
  // bijective XCD swizzle: 1536 blocks, 192 per XCD (1536%8==0)
  const int fid = blockIdx.x + (blockIdx.y << 3);
  const int nid = (fid & 7) * 192 + (fid >> 3);
  const int bx = nid & 7, by = nid >> 3;
  const int sel = by >> 6;
  const int m0 = (by & 63) * 128, n0 = bx * 128;
  const int lr = lane & 15, lg = lane >> 4;

  const int srow = lane >> 3;
  const int scl8 = (lane & 7) ^ srow;
  const __bf16* A  = Abase + sel * 8388608;
  const __bf16* BT = Wbase + sel * 1048576;
  const __bf16* Ab = A + (m0 + wid * 32 + srow) * 1024 + scl8 * 8;
  const __bf16* Bb = BT + (n0 + wid * 32 + srow) * 1024 + scl8 * 8;
  char* AsW = smem + wid * 4096;
  char* BsW = smem + 16384 + wid * 4096;

  f32x4 acc[4][4] = {};

  for (int k0 = 0; k0 < 1024; k0 += 64) {
#pragma unroll
    for (int i = 0; i < 4; ++i) {
      gl16(Ab + i * 8192 + k0, AsW + i * 1024);
      gl16(Bb + i * 8192 + k0, BsW + i * 1024);
    }
    __syncthreads();
#pragma unroll
    for (int ks = 0; ks < 2; ++ks) {
      bf16x8 af[4], bfv[4];
      const int co = (ks * 64 + lg * 16) ^ ((lr & 7) << 4);
#pragma unroll
      for (int i = 0; i < 4; ++i) {
        af[i]  = *(const bf16x8*)(smem + (wr * 64 + i * 16 + lr) * 128 + co);
        bfv[i] = *(const bf16x8*)(smem + 16384 + (wc * 64 + i * 16 + lr) * 128 + co);
      }
#pragma unroll
      for (int i = 0; i < 4; ++i)
#pragma unroll
        for (int j = 0; j < 4; ++j)
          acc[i][j] = __builtin_amdgcn_mfma_f32_16x16x32_bf16(af[i], bfv[j], acc[i][j], 0, 0, 0);
    }
    __syncthreads();
  }

  const float* bias = sel == 0 ? bq : (sel == 1 ? bk : bv);
  const float bsc = sel == 0 ? sclq : 1.f;
  __bf16* outp = sel == 0 ? Qp : (sel == 1 ? Kp : Vtp);
#pragma unroll
  for (int i = 0; i < 4; ++i)
#pragma unroll
    for (int j = 0; j < 4; ++j) {
      const int n = n0 + wc * 64 + j * 16 + lr;
      const float bb = bias[n] * bsc;
#pragma unroll
      for (int r = 0; r < 4; ++r) {
        const int m = m0 + wr * 64 + i * 16 + lg * 4 + r;
        const float v = acc[i][j][r] + bb;
        const int b = m >> 11, s = m & 2047;
        const int h = n >> 6, dh = n & 63;
        if (sel < 2)
          outp[(((b * 16 + h) * 2048 + s) << 6) + dh] = (__bf16)v;
        else
          outp[(((b * 16 + h) * 64 + dh) << 11) + s] = (__bf16)v;
      }
    }
}

// ---------------------------------------------------------------------------
// Output projection GEMM: out f32 = ctx(bf16) * WoT^T + bo. XCD-swizzled.
// ---------------------------------------------------------------------------
__global__ __launch_bounds__(256) void gemm_o(const __bf16* __restrict__ A,
                                              const __bf16* __restrict__ BT,
                                              const float* __restrict__ bias,
                                              float* __restrict__ outp) {
  __shared__ __align__(16) char smem[32768];
  const int tid = threadIdx.x, wid = tid >> 6, lane = tid & 63;
  const int wr = wid >> 1, wc = wid & 1;
  // bijective XCD swizzle: 512 blocks, 64 per XCD
  const int fid = blockIdx.x + (blockIdx.y << 3);
  const int nid = (fid & 7) * 64 + (fid >> 3);
  const int m0 = (nid >> 3) * 128, n0 = (nid & 7) * 128;
  const int lr = lane & 15, lg = lane >> 4;

  const int srow = lane >> 3;
  const int scl8 = (lane & 7) ^ srow;
  const __bf16* Ab = A + (m0 + wid * 32 + srow) * 1024 + scl8 * 8;
  const __bf16* Bb = BT + (n0 + wid * 32 + srow) * 1024 + scl8 * 8;
  char* AsW = smem + wid * 4096;
  char* BsW = smem + 16384 + wid * 4096;

  f32x4 acc[4][4] = {};

  for (int k0 = 0; k0 < 1024; k0 += 64) {
#pragma unroll
    for (int i = 0; i < 4; ++i) {
      gl16(Ab + i * 8192 + k0, AsW + i * 1024);
      gl16(Bb + i * 8192 + k0, BsW + i * 1024);
    }
    __syncthreads();
#pragma unroll
    for (int ks = 0; ks < 2; ++ks) {
      bf16x8 af[4], bfv[4];
      const int co = (ks * 64 + lg * 16) ^ ((lr & 7) << 4);
#pragma unroll
      for (int i = 0; i < 4; ++i) {
        af[i]  = *(const bf16x8*)(smem + (wr * 64 + i * 16 + lr) * 128 + co);
        bfv[i] = *(const bf16x8*)(smem + 16384 + (wc * 64 + i * 16 + lr) * 128 + co);
      }
#pragma unroll
      for (int i = 0; i < 4; ++i)
#pragma unroll
        for (int j = 0; j < 4; ++j)
          acc[i][j] = __builtin_amdgcn_mfma_f32_16x16x32_bf16(af[i], bfv[j], acc[i][j], 0, 0, 0);
    }
    __syncthreads();
  }

#pragma unroll
  for (int i = 0; i < 4; ++i)
#pragma unroll
    for (int j = 0; j < 4; ++j) {
      const int n = n0 + wc * 64 + j * 16 + lr;
      const float bb = bias[n];
#pragma unroll
      for (int r = 0; r < 4; ++r) {
        const int m = m0 + wr * 64 + i * 16 + lg * 4 + r;
        outp[m * 1024 + n] = acc[i][j][r] + bb;
      }
    }
}

// ---------------------------------------------------------------------------
// Flash attention, QBLK=32 per wave, 128 q-rows per block. XCD-swizzled so
// the 16 q-blocks of a head colocate (K/V L2-resident: 8 heads x 512KB/XCD).
// Swapped QK^T (lane owns q=lr); defer-max softmax (T13, THR=8 in log2 dom).
// ---------------------------------------------------------------------------
__global__ __launch_bounds__(256) void attn_k(const __bf16* __restrict__ Qp,
                                              const __bf16* __restrict__ Kp,
                                              const __bf16* __restrict__ Vt,
                                              __bf16* __restrict__ ctx) {
  __shared__ __align__(16) char smem[40960];
  // Ks: 2x8KB @0 ; Vs: 2x8KB @16384 ; Ps: 4 waves x 2KB @32768
  const int tid = threadIdx.x, wid = tid >> 6, lane = tid & 63;
  const int lr = lane & 15, lg = lane >> 4;
  // bijective XCD swizzle: 1024 blocks, 128 per XCD
  const int fid = blockIdx.x + (blockIdx.y << 4);
  const int nid = (fid & 7) * 128 + (fid >> 3);
  const int bh = nid >> 4;
  const int q0 = (nid & 15) * 128 + wid * 32;
  const int S = 2048;

  const int srow = lane >> 3;
  const int scl8 = (lane & 7) ^ srow;
  const __bf16* Kbase = Kp + (bh * S + srow) * 64 + scl8 * 8;
  const __bf16* Vbase = Vt + (bh * 64 + srow) * S + scl8 * 8;
  char* Ps = smem + 32768 + wid * 2048;

  bf16x8 aq[2][2];
#pragma unroll
  for (int qs = 0; qs < 2; ++qs)
#pragma unroll
    for (int ks = 0; ks < 2; ++ks)
      aq[qs][ks] = *(const bf16x8*)(Qp + (bh * S + q0 + qs * 16 + lr) * 64 +
                                    ks * 32 + lg * 8);

  float m_run[2] = {-1e30f, -1e30f}, l_run[2] = {0.f, 0.f};
  f32x4 acc_o[2][4] = {};

  // prologue: stage tile 0 -> buf 0 (chunks wid*2, wid*2+1)
#pragma unroll
  for (int i = 0; i < 2; ++i) {
    const int ch = wid * 2 + i;
    gl16(Kbase + ch * 512, smem + ch * 1024);
    gl16(Vbase + ch * 16384, smem + 16384 + ch * 1024);
  }

  int cur = 0;
  for (int t = 0; t < 32; ++t) {
    __syncthreads(); // drain vmcnt -> buf[cur] ready; all prev reads done
    if (t + 1 < 32) {
      const int kv1 = (t + 1) * 64;
      char* Kd = smem + (cur ^ 1) * 8192;
      char* Vd = smem + 16384 + (cur ^ 1) * 8192;
#pragma unroll
      for (int i = 0; i < 2; ++i) {
        const int ch = wid * 2 + i;
        gl16(Kbase + kv1 * 64 + ch * 512, Kd + ch * 1024);
        gl16(Vbase + kv1 + ch * 16384, Vd + ch * 1024);
      }
    }
    const char* Ks = smem + cur * 8192;
    const char* Vs = smem + 16384 + cur * 8192;

    // ---- QK^T: K frags shared across both q-sets ----
    f32x4 sc[2][4] = {};
    __builtin_amdgcn_s_setprio(1);
#pragma unroll
    for (int cb = 0; cb < 4; ++cb) {
#pragma unroll
      for (int ks = 0; ks < 2; ++ks) {
        const int krow = cb * 16 + lr;
        const bf16x8 kf = *(const bf16x8*)(Ks + krow * 128 +
                                           ((ks * 64 + lg * 16) ^ ((krow & 7) << 4)));
        sc[0][cb] = __builtin_amdgcn_mfma_f32_16x16x32_bf16(kf, aq[0][ks], sc[0][cb], 0, 0, 0);
        sc[1][cb] = __builtin_amdgcn_mfma_f32_16x16x32_bf16(kf, aq[1][ks], sc[1][cb], 0, 0, 0);
      }
    }
    __builtin_amdgcn_s_setprio(0);

    // ---- online softmax with defer-max; Ps reused sequentially ----
    bf16x8 pa[2][2];
#pragma unroll
    for (int qs = 0; qs < 2; ++qs) {
      float mx = sc[qs][0][0];
#pragma unroll
      for (int cb = 0; cb < 4; ++cb)
#pragma unroll
        for (int r = 0; r < 4; ++r) mx = fmaxf(mx, sc[qs][cb][r]);
      mx = fmaxf(mx, __shfl_xor(mx, 16, 64));
      mx = fmaxf(mx, __shfl_xor(mx, 32, 64));
      // T13 defer-max: only rescale when some row's max grew by > 8 (log2)
      if (!__all(mx <= m_run[qs] + 8.f)) {
        const float mnew = fmaxf(m_run[qs], mx);
        const float corr = __builtin_amdgcn_exp2f(m_run[qs] - mnew);
        m_run[qs] = mnew;
        l_run[qs] *= corr;
        float corrv[4];
#pragma unroll
        for (int r = 0; r < 4; ++r) corrv[r] = __shfl(corr, lg * 4 + r, 64);
#pragma unroll
        for (int dhb = 0; dhb < 4; ++dhb)
#pragma unroll
          for (int r = 0; r < 4; ++r) acc_o[qs][dhb][r] *= corrv[r];
      }
      float rs = 0.f;
#pragma unroll
      for (int cb = 0; cb < 4; ++cb) {
        bf16x4 pk;
#pragma unroll
        for (int r = 0; r < 4; ++r) {
          const float p = __builtin_amdgcn_exp2f(sc[qs][cb][r] - m_run[qs]);
          rs += p;
          pk[r] = (__bf16)p;
        }
        *(bf16x4*)(Ps + lr * 128 + ((cb * 32 + lg * 8) ^ ((lr & 7) << 4))) = pk;
      }
      rs += __shfl_xor(rs, 16, 64);
      rs += __shfl_xor(rs, 32, 64);
      l_run[qs] += rs;
      // read back P fragments (wave-local RAW -> lgkmcnt, no barrier)
#pragma unroll
      for (int ks = 0; ks < 2; ++ks)
        pa[qs][ks] = *(const bf16x8*)(Ps + lr * 128 +
                                      ((ks * 64 + lg * 16) ^ ((lr & 7) << 4)));
    }

    // ---- PV: V frags shared across both q-sets ----
    __builtin_amdgcn_s_setprio(1);
#pragma unroll
    for (int dhb = 0; dhb < 4; ++dhb) {
#pragma unroll
      for (int ks = 0; ks < 2; ++ks) {
        const int vrow = dhb * 16 + lr;
        const bf16x8 vf = *(const bf16x8*)(Vs + vrow * 128 +
                                           ((ks * 64 + lg * 16) ^ ((vrow & 7) << 4)));
        acc_o[0][dhb] = __builtin_amdgcn_mfma_f32_16x16x32_bf16(pa[0][ks], vf, acc_o[0][dhb], 0, 0, 0);
        acc_o[1][dhb] = __builtin_amdgcn_mfma_f32_16x16x32_bf16(pa[1][ks], vf, acc_o[1][dhb], 0, 0, 0);
      }
    }
    __builtin_amdgcn_s_setprio(0);
    cur ^= 1;
  }

  // ---- epilogue: ctx[b][s][h*64+dh] = acc / l ----
  const int b = bh >> 4, h = bh & 15;
#pragma unroll
  for (int qs = 0; qs < 2; ++qs) {
    float linv[4];
#pragma unroll
    for (int r = 0; r < 4; ++r) linv[r] = 1.f / __shfl(l_run[qs], lg * 4 + r, 64);
#pragma unroll
    for (int dhb = 0; dhb < 4; ++dhb)
#pragma unroll
      for (int r = 0; r < 4; ++r) {
        const int sr = q0 + qs * 16 + lg * 4 + r;
        const int d = h * 64 + dhb * 16 + lr;
        ctx[(b * 2048 + sr) * 1024 + d] = (__bf16)(acc_o[qs][dhb][r] * linv[r]);
      }
  }
}

// ---------------------------------------------------------------------------
extern "C" void kernel_launch(void* const* d_in, const int* in_sizes, int n_in,
                              void* d_out, int out_size, void* d_ws, size_t ws_size,
                              hipStream_t stream) {
  const float* query = (const float*)d_in[0];
  const float* key   = (const float*)d_in[1];
  const float* value = (const float*)d_in[2];
  const float* Wq = (const float*)d_in[3];
  const float* bq = (const float*)d_in[4];
  const float* Wk = (const float*)d_in[5];
  const float* bk = (const float*)d_in[6];
  const float* Wv = (const float*)d_in[7];
  const float* bv = (const float*)d_in[8];
  const float* Wo = (const float*)d_in[9];
  const float* bo = (const float*)d_in[10];

  char* ws = (char*)d_ws;
  const size_t MiB = 1048576;
  __bf16* Wqkv = (__bf16*)(ws);            // WqT@0, WkT@2MiB, WvT@4MiB
  __bf16* WoT  = (__bf16*)(ws + 6 * MiB);
  __bf16* Abf  = (__bf16*)(ws + 8 * MiB);  // 3 x 16MiB (q,k,v bf16); slot0 reused as ctx
  __bf16* Qp   = (__bf16*)(ws + 56 * MiB);
  __bf16* Kp   = (__bf16*)(ws + 72 * MiB);
  __bf16* Vt   = (__bf16*)(ws + 88 * MiB);
  __bf16* ctx  = Abf;

  const float SCL = 0.125f * 1.44269504088896340736f; // fold /8 and log2(e) into Q

  const dim3 tb(32, 8);
  wt_cvt<<<dim3(32, 32), tb, 0, stream>>>(Wq, Wqkv,              SCL);
  wt_cvt<<<dim3(32, 32), tb, 0, stream>>>(Wk, Wqkv + 1048576,    1.f);
  wt_cvt<<<dim3(32, 32), tb, 0, stream>>>(Wv, Wqkv + 2097152,    1.f);
  wt_cvt<<<dim3(32, 32), tb, 0, stream>>>(Wo, WoT,               1.f);

  cvt_k<<<4096, 256, 0, stream>>>(query, Abf);
  cvt_k<<<4096, 256, 0, stream>>>(key,   Abf + 8388608);
  cvt_k<<<4096, 256, 0, stream>>>(value, Abf + 16777216);

  gemm_qkv<<<dim3(8, 192), 256, 0, stream>>>(Abf, Wqkv, bq, bk, bv, SCL, Qp, Kp, Vt);

  attn_k<<<dim3(16, 64), 256, 0, stream>>>(Qp, Kp, Vt, ctx);

  gemm_o<<<dim3(8, 64), 256, 0, stream>>>(ctx, WoT, bo, (float*)d_out);
}

// Round 12
// 370.304 us; speedup vs baseline: 1.1223x; 1.0603x over previous
//
#include <hip/hip_runtime.h>

// ---------------------------------------------------------------------------
// MHA forward: B=4, S=2048, D=1024, H=16, DH=64
// bf16 MFMA (16x16x32), f32 accumulate.
// r12 changes: (T3-min) 2-phase double-buffered GEMMs (issue next K-tile's
//              global_load_lds BEFORE computing current; 1 barrier/K-step);
//              fuse 4x wt_cvt -> 1 and 3x cvt_k -> 1 (10 -> 5 launches).
// attn_k byte-identical to r11 (control; XCD swizzle + defer-max validated).
// ---------------------------------------------------------------------------

typedef __bf16 bf16x8 __attribute__((ext_vector_type(8)));
typedef __bf16 bf16x4 __attribute__((ext_vector_type(4)));
typedef float f32x4 __attribute__((ext_vector_type(4)));

#define GLAS __attribute__((address_space(1)))
#define LDSAS __attribute__((address_space(3)))

__device__ __forceinline__ void gl16(const void* g, void* l) {
  __builtin_amdgcn_global_load_lds((GLAS void*)const_cast<void*>(g),
                                   (LDSAS void*)l, 16, 0, 0);
}

// ---------------------------------------------------------------------------
// Fused weight transpose + f32->bf16 (+scale): 4 weights in one launch.
// grid (32, 128): wsel = by>>5 (0=Wq,1=Wk,2=Wv,3=Wo), k0 = (by&31)*32.
// ---------------------------------------------------------------------------
__global__ __launch_bounds__(256) void wt_cvt4(const float* __restrict__ wq,
                                               const float* __restrict__ wk,
                                               const float* __restrict__ wv,
                                               const float* __restrict__ wo,
                                               __bf16* __restrict__ wt4, float sclq) {
  __shared__ float t[32][33];
  const int wsel = blockIdx.y >> 5;
  const float* w = wsel == 0 ? wq : (wsel == 1 ? wk : (wsel == 2 ? wv : wo));
  const float scl = wsel == 0 ? sclq : 1.f;
  __bf16* wt = wt4 + wsel * 1048576;
  const int n0 = blockIdx.x * 32, k0 = (blockIdx.y & 31) * 32;
  const int x = threadIdx.x, y = threadIdx.y; // 32 x 8
#pragma unroll
  for (int i = 0; i < 32; i += 8) t[y + i][x] = w[(k0 + y + i) * 1024 + n0 + x];
  __syncthreads();
#pragma unroll
  for (int i = 0; i < 32; i += 8)
    wt[(n0 + y + i) * 1024 + (k0 + x)] = (__bf16)(t[x][y + i] * scl);
}

// ---------------------------------------------------------------------------
// Fused activation f32 -> bf16 (q,k,v in one launch). grid 12288.
// ---------------------------------------------------------------------------
__global__ __launch_bounds__(256) void cvt_k3(const float* __restrict__ q,
                                              const float* __restrict__ k,
                                              const float* __restrict__ v,
                                              __bf16* __restrict__ out) {
  const int sel = blockIdx.x >> 12;
  const float* in = sel == 0 ? q : (sel == 1 ? k : v);
  const int i = ((blockIdx.x & 4095) * 256 + threadIdx.x) * 8;
  const float4 f0 = *(const float4*)(in + i);
  const float4 f1 = *(const float4*)(in + i + 4);
  bf16x8 o;
  o[0] = (__bf16)f0.x; o[1] = (__bf16)f0.y; o[2] = (__bf16)f0.z; o[3] = (__bf16)f0.w;
  o[4] = (__bf16)f1.x; o[5] = (__bf16)f1.y; o[6] = (__bf16)f1.z; o[7] = (__bf16)f1.w;
  *(bf16x8*)(out + sel * 8388608 + i) = o;
}

// ---------------------------------------------------------------------------
// Fused QKV projection GEMM, 2-phase double-buffered.
// 1536 blocks, XCD-swizzled. sel = by>>6, m0 = (by&63)*128, n0 = bx*128.
// LDS 64KB: A dbuf 2x16KB @0, B dbuf 2x16KB @32768.
// Loop: barrier (waits tile-t loads, issued one iter ago) -> issue t+1 ->
//       compute t. Load latency hides under previous iter's MFMA phase.
// ---------------------------------------------------------------------------
__global__ __launch_bounds__(256) void gemm_qkv(
    const __bf16* __restrict__ Abase, const __bf16* __restrict__ Wbase,
    const float* __restrict__ bq, const float* __restrict__ bk,
    const float* __restrict__ bv, float sclq,
    __bf16* __restrict__ Qp, __bf16* __restrict__ Kp, __bf16* __restrict__ Vtp) {
  __shared__ __align__(16) char smem[65536];
  const int tid = threadIdx.x, wid = tid >> 6, lane = tid & 63;
  const int wr = wid >> 1, wc = wid & 1;
  // bijective XCD swizzle: 1536 blocks, 192 per XCD
  const int fid = blockIdx.x + (blockIdx.y << 3);
  const int nid = (fid & 7) * 192 + (fid >> 3);
  const int bx = nid & 7, by = nid >> 3;
  const int sel = by >> 6;
  const int m0 = (by & 63) * 128, n0 = bx * 128;
  const int lr = lane & 15, lg = lane >> 4;

  const int srow = lane >> 3;
  const int scl8 = (lane & 7) ^ srow;
  const __bf16* A  = Abase + sel * 8388608;
  const __bf16* BT = Wbase + sel * 1048576;
  const __bf16* Ab = A + (m0 + wid * 32 + srow) * 1024 + scl8 * 8;
  const __bf16* Bb = BT + (n0 + wid * 32 + srow) * 1024 + scl8 * 8;

  f32x4 acc[4][4] = {};

  // prologue: stage tile 0 into buf 0
#pragma unroll
  for (int i = 0; i < 4; ++i) {
    gl16(Ab + i * 8192, smem + wid * 4096 + i * 1024);
    gl16(Bb + i * 8192, smem + 32768 + wid * 4096 + i * 1024);
  }

  int cur = 0;
  for (int k0 = 0; k0 < 1024; k0 += 64) {
    __syncthreads(); // waits tile-t loads (vmcnt) + prev iter's ds_reads
    if (k0 + 64 < 1024) {
      char* Ad = smem + (cur ^ 1) * 16384 + wid * 4096;
      char* Bd = smem + 32768 + (cur ^ 1) * 16384 + wid * 4096;
#pragma unroll
      for (int i = 0; i < 4; ++i) {
        gl16(Ab + i * 8192 + k0 + 64, Ad + i * 1024);
        gl16(Bb + i * 8192 + k0 + 64, Bd + i * 1024);
      }
    }
    const char* As = smem + cur * 16384;
    const char* Bs = smem + 32768 + cur * 16384;
#pragma unroll
    for (int ks = 0; ks < 2; ++ks) {
      bf16x8 af[4], bfv[4];
      const int co = (ks * 64 + lg * 16) ^ ((lr & 7) << 4);
#pragma unroll
      for (int i = 0; i < 4; ++i) {
        af[i]  = *(const bf16x8*)(As + (wr * 64 + i * 16 + lr) * 128 + co);
        bfv[i] = *(const bf16x8*)(Bs + (wc * 64 + i * 16 + lr) * 128 + co);
      }
#pragma unroll
      for (int i = 0; i < 4; ++i)
#pragma unroll
        for (int j = 0; j < 4; ++j)
          acc[i][j] = __builtin_amdgcn_mfma_f32_16x16x32_bf16(af[i], bfv[j], acc[i][j], 0, 0, 0);
    }
    cur ^= 1;
  }

  const float* bias = sel == 0 ? bq : (sel == 1 ? bk : bv);
  const float bsc = sel == 0 ? sclq : 1.f;
  __bf16* outp = sel == 0 ? Qp : (sel == 1 ? Kp : Vtp);
#pragma unroll
  for (int i = 0; i < 4; ++i)
#pragma unroll
    for (int j = 0; j < 4; ++j) {
      const int n = n0 + wc * 64 + j * 16 + lr;
      const float bb = bias[n] * bsc;
#pragma unroll
      for (int r = 0; r < 4; ++r) {
        const int m = m0 + wr * 64 + i * 16 + lg * 4 + r;
        const float v = acc[i][j][r] + bb;
        const int b = m >> 11, s = m & 2047;
        const int h = n >> 6, dh = n & 63;
        if (sel < 2)
          outp[(((b * 16 + h) * 2048 + s) << 6) + dh] = (__bf16)v;
        else
          outp[(((b * 16 + h) * 64 + dh) << 11) + s] = (__bf16)v;
      }
    }
}

// ---------------------------------------------------------------------------
// Output projection GEMM, 2-phase double-buffered. XCD-swizzled, 512 blocks.
// ---------------------------------------------------------------------------
__global__ __launch_bounds__(256) void gemm_o(const __bf16* __restrict__ A,
                                              const __bf16* __restrict__ BT,
                                              const float* __restrict__ bias,
                                              float* __restrict__ outp) {
  __shared__ __align__(16) char smem[65536];
  const int tid = threadIdx.x, wid = tid >> 6, lane = tid & 63;
  const int wr = wid >> 1, wc = wid & 1;
  const int fid = blockIdx.x + (blockIdx.y << 3);
  const int nid = (fid & 7) * 64 + (fid >> 3);
  const int m0 = (nid >> 3) * 128, n0 = (nid & 7) * 128;
  const int lr = lane & 15, lg = lane >> 4;

  const int srow = lane >> 3;
  const int scl8 = (lane & 7) ^ srow;
  const __bf16* Ab = A + (m0 + wid * 32 + srow) * 1024 + scl8 * 8;
  const __bf16* Bb = BT + (n0 + wid * 32 + srow) * 1024 + scl8 * 8;

  f32x4 acc[4][4] = {};

#pragma unroll
  for (int i = 0; i < 4; ++i) {
    gl16(Ab + i * 8192, smem + wid * 4096 + i * 1024);
    gl16(Bb + i * 8192, smem + 32768 + wid * 4096 + i * 1024);
  }

  int cur = 0;
  for (int k0 = 0; k0 < 1024; k0 += 64) {
    __syncthreads();
    if (k0 + 64 < 1024) {
      char* Ad = smem + (cur ^ 1) * 16384 + wid * 4096;
      char* Bd = smem + 32768 + (cur ^ 1) * 16384 + wid * 4096;
#pragma unroll
      for (int i = 0; i < 4; ++i) {
        gl16(Ab + i * 8192 + k0 + 64, Ad + i * 1024);
        gl16(Bb + i * 8192 + k0 + 64, Bd + i * 1024);
      }
    }
    const char* As = smem + cur * 16384;
    const char* Bs = smem + 32768 + cur * 16384;
#pragma unroll
    for (int ks = 0; ks < 2; ++ks) {
      bf16x8 af[4], bfv[4];
      const int co = (ks * 64 + lg * 16) ^ ((lr & 7) << 4);
#pragma unroll
      for (int i = 0; i < 4; ++i) {
        af[i]  = *(const bf16x8*)(As + (wr * 64 + i * 16 + lr) * 128 + co);
        bfv[i] = *(const bf16x8*)(Bs + (wc * 64 + i * 16 + lr) * 128 + co);
      }
#pragma unroll
      for (int i = 0; i < 4; ++i)
#pragma unroll
        for (int j = 0; j < 4; ++j)
          acc[i][j] = __builtin_amdgcn_mfma_f32_16x16x32_bf16(af[i], bfv[j], acc[i][j], 0, 0, 0);
    }
    cur ^= 1;
  }

#pragma unroll
  for (int i = 0; i < 4; ++i)
#pragma unroll
    for (int j = 0; j < 4; ++j) {
      const int n = n0 + wc * 64 + j * 16 + lr;
      const float bb = bias[n];
#pragma unroll
      for (int r = 0; r < 4; ++r) {
        const int m = m0 + wr * 64 + i * 16 + lg * 4 + r;
        outp[m * 1024 + n] = acc[i][j][r] + bb;
      }
    }
}

// ---------------------------------------------------------------------------
// Flash attention (byte-identical to r11). QBLK=32/wave, 128 q-rows/block,
// XCD-swizzled, swapped QK^T, defer-max (T13), dbuf K/V via global_load_lds.
// ---------------------------------------------------------------------------
__global__ __launch_bounds__(256) void attn_k(const __bf16* __restrict__ Qp,
                                              const __bf16* __restrict__ Kp,
                                              const __bf16* __restrict__ Vt,
                                              __bf16* __restrict__ ctx) {
  __shared__ __align__(16) char smem[40960];
  // Ks: 2x8KB @0 ; Vs: 2x8KB @16384 ; Ps: 4 waves x 2KB @32768
  const int tid = threadIdx.x, wid = tid >> 6, lane = tid & 63;
  const int lr = lane & 15, lg = lane >> 4;
  const int fid = blockIdx.x + (blockIdx.y << 4);
  const int nid = (fid & 7) * 128 + (fid >> 3);
  const int bh = nid >> 4;
  const int q0 = (nid & 15) * 128 + wid * 32;
  const int S = 2048;

  const int srow = lane >> 3;
  const int scl8 = (lane & 7) ^ srow;
  const __bf16* Kbase = Kp + (bh * S + srow) * 64 + scl8 * 8;
  const __bf16* Vbase = Vt + (bh * 64 + srow) * S + scl8 * 8;
  char* Ps = smem + 32768 + wid * 2048;

  bf16x8 aq[2][2];
#pragma unroll
  for (int qs = 0; qs < 2; ++qs)
#pragma unroll
    for (int ks = 0; ks < 2; ++ks)
      aq[qs][ks] = *(const bf16x8*)(Qp + (bh * S + q0 + qs * 16 + lr) * 64 +
                                    ks * 32 + lg * 8);

  float m_run[2] = {-1e30f, -1e30f}, l_run[2] = {0.f, 0.f};
  f32x4 acc_o[2][4] = {};

#pragma unroll
  for (int i = 0; i < 2; ++i) {
    const int ch = wid * 2 + i;
    gl16(Kbase + ch * 512, smem + ch * 1024);
    gl16(Vbase + ch * 16384, smem + 16384 + ch * 1024);
  }

  int cur = 0;
  for (int t = 0; t < 32; ++t) {
    __syncthreads();
    if (t + 1 < 32) {
      const int kv1 = (t + 1) * 64;
      char* Kd = smem + (cur ^ 1) * 8192;
      char* Vd = smem + 16384 + (cur ^ 1) * 8192;
#pragma unroll
      for (int i = 0; i < 2; ++i) {
        const int ch = wid * 2 + i;
        gl16(Kbase + kv1 * 64 + ch * 512, Kd + ch * 1024);
        gl16(Vbase + kv1 + ch * 16384, Vd + ch * 1024);
      }
    }
    const char* Ks = smem + cur * 8192;
    const char* Vs = smem + 16384 + cur * 8192;

    f32x4 sc[2][4] = {};
    __builtin_amdgcn_s_setprio(1);
#pragma unroll
    for (int cb = 0; cb < 4; ++cb) {
#pragma unroll
      for (int ks = 0; ks < 2; ++ks) {
        const int krow = cb * 16 + lr;
        const bf16x8 kf = *(const bf16x8*)(Ks + krow * 128 +
                                           ((ks * 64 + lg * 16) ^ ((krow & 7) << 4)));
        sc[0][cb] = __builtin_amdgcn_mfma_f32_16x16x32_bf16(kf, aq[0][ks], sc[0][cb], 0, 0, 0);
        sc[1][cb] = __builtin_amdgcn_mfma_f32_16x16x32_bf16(kf, aq[1][ks], sc[1][cb], 0, 0, 0);
      }
    }
    __builtin_amdgcn_s_setprio(0);

    bf16x8 pa[2][2];
#pragma unroll
    for (int qs = 0; qs < 2; ++qs) {
      float mx = sc[qs][0][0];
#pragma unroll
      for (int cb = 0; cb < 4; ++cb)
#pragma unroll
        for (int r = 0; r < 4; ++r) mx = fmaxf(mx, sc[qs][cb][r]);
      mx = fmaxf(mx, __shfl_xor(mx, 16, 64));
      mx = fmaxf(mx, __shfl_xor(mx, 32, 64));
      if (!__all(mx <= m_run[qs] + 8.f)) {
        const float mnew = fmaxf(m_run[qs], mx);
        const float corr = __builtin_amdgcn_exp2f(m_run[qs] - mnew);
        m_run[qs] = mnew;
        l_run[qs] *= corr;
        float corrv[4];
#pragma unroll
        for (int r = 0; r < 4; ++r) corrv[r] = __shfl(corr, lg * 4 + r, 64);
#pragma unroll
        for (int dhb = 0; dhb < 4; ++dhb)
#pragma unroll
          for (int r = 0; r < 4; ++r) acc_o[qs][dhb][r] *= corrv[r];
      }
      float rs = 0.f;
#pragma unroll
      for (int cb = 0; cb < 4; ++cb) {
        bf16x4 pk;
#pragma unroll
        for (int r = 0; r < 4; ++r) {
          const float p = __builtin_amdgcn_exp2f(sc[qs][cb][r] - m_run[qs]);
          rs += p;
          pk[r] = (__bf16)p;
        }
        *(bf16x4*)(Ps + lr * 128 + ((cb * 32 + lg * 8) ^ ((lr & 7) << 4))) = pk;
      }
      rs += __shfl_xor(rs, 16, 64);
      rs += __shfl_xor(rs, 32, 64);
      l_run[qs] += rs;
#pragma unroll
      for (int ks = 0; ks < 2; ++ks)
        pa[qs][ks] = *(const bf16x8*)(Ps + lr * 128 +
                                      ((ks * 64 + lg * 16) ^ ((lr & 7) << 4)));
    }

    __builtin_amdgcn_s_setprio(1);
#pragma unroll
    for (int dhb = 0; dhb < 4; ++dhb) {
#pragma unroll
      for (int ks = 0; ks < 2; ++ks) {
        const int vrow = dhb * 16 + lr;
        const bf16x8 vf = *(const bf16x8*)(Vs + vrow * 128 +
                                           ((ks * 64 + lg * 16) ^ ((vrow & 7) << 4)));
        acc_o[0][dhb] = __builtin_amdgcn_mfma_f32_16x16x32_bf16(pa[0][ks], vf, acc_o[0][dhb], 0, 0, 0);
        acc_o[1][dhb] = __builtin_amdgcn_mfma_f32_16x16x32_bf16(pa[1][ks], vf, acc_o[1][dhb], 0, 0, 0);
      }
    }
    __builtin_amdgcn_s_setprio(0);
    cur ^= 1;
  }

  const int b = bh >> 4, h = bh & 15;
#pragma unroll
  for (int qs = 0; qs < 2; ++qs) {
    float linv[4];
#pragma unroll
    for (int r = 0; r < 4; ++r) linv[r] = 1.f / __shfl(l_run[qs], lg * 4 + r, 64);
#pragma unroll
    for (int dhb = 0; dhb < 4; ++dhb)
#pragma unroll
      for (int r = 0; r < 4; ++r) {
        const int sr = q0 + qs * 16 + lg * 4 + r;
        const int d = h * 64 + dhb * 16 + lr;
        ctx[(b * 2048 + sr) * 1024 + d] = (__bf16)(acc_o[qs][dhb][r] * linv[r]);
      }
  }
}

// ---------------------------------------------------------------------------
extern "C" void kernel_launch(void* const* d_in, const int* in_sizes, int n_in,
                              void* d_out, int out_size, void* d_ws, size_t ws_size,
                              hipStream_t stream) {
  const float* query = (const float*)d_in[0];
  const float* key   = (const float*)d_in[1];
  const float* value = (const float*)d_in[2];
  const float* Wq = (const float*)d_in[3];
  const float* bq = (const float*)d_in[4];
  const float* Wk = (const float*)d_in[5];
  const float* bk = (const float*)d_in[6];
  const float* Wv = (const float*)d_in[7];
  const float* bv = (const float*)d_in[8];
  const float* Wo = (const float*)d_in[9];
  const float* bo = (const float*)d_in[10];

  char* ws = (char*)d_ws;
  const size_t MiB = 1048576;
  __bf16* Wt4 = (__bf16*)(ws);             // WqT@0, WkT@2MiB, WvT@4MiB, WoT@6MiB
  __bf16* Abf = (__bf16*)(ws + 8 * MiB);   // 3 x 16MiB; slot0 reused as ctx
  __bf16* Qp  = (__bf16*)(ws + 56 * MiB);
  __bf16* Kp  = (__bf16*)(ws + 72 * MiB);
  __bf16* Vt  = (__bf16*)(ws + 88 * MiB);
  __bf16* ctx = Abf;

  const float SCL = 0.125f * 1.44269504088896340736f; // fold /8 and log2(e) into Q

  wt_cvt4<<<dim3(32, 128), dim3(32, 8), 0, stream>>>(Wq, Wk, Wv, Wo, Wt4, SCL);
  cvt_k3<<<12288, 256, 0, stream>>>(query, key, value, Abf);

  gemm_qkv<<<dim3(8, 192), 256, 0, stream>>>(Abf, Wt4, bq, bk, bv, SCL, Qp, Kp, Vt);

  attn_k<<<dim3(16, 64), 256, 0, stream>>>(Qp, Kp, Vt, ctx);

  gemm_o<<<dim3(8, 64), 256, 0, stream>>>(ctx, Wt4 + 3145728, bo, (float*)d_out);
}